// Round 2
// baseline (244.878 us; speedup 1.0000x reference)
//
#include <hip/hip_runtime.h>
#include <stdint.h>

// ---------------------------------------------------------------------------
// GCN 2-layer. R12: aggp pad-to-8 buckets via zero-row (id=N -> zw row N = 0),
// kills the serial tail loop; 16-deep gather MLP (16-edge batch + 8-edge rem).
// k5 fill 8 edges/thread. gemm2k M=64/256thr (782 blocks, better CU balance).
// 5 dispatches: k0(zero cursor+zwpad+g_out | prep_w) -> k5(gemm1 (+) fill) ->
// aggp1 -> gemm2 -> aggp2.
// ---------------------------------------------------------------------------

#define CAP 96

typedef __attribute__((ext_vector_type(8))) short short8;
typedef __attribute__((ext_vector_type(4))) float f32x4;

__device__ __forceinline__ uint16_t bf16rne(float f) {
    uint32_t u = __float_as_uint(f);
    uint32_t r = (u + 0x7fffu + ((u >> 16) & 1u)) >> 16;
    return (uint16_t)r;
}
__device__ __forceinline__ float bf_lo(uint32_t v) { return __uint_as_float(v << 16); }
__device__ __forceinline__ float bf_hi(uint32_t v) { return __uint_as_float(v & 0xffff0000u); }

// ---- K0 (512 thr): zero cursor(N+1) + zw pad row | prep_w | zero g_out ----
__global__ __launch_bounds__(512) void k0(int* __restrict__ cursor, int nbC, int N,
                                          const float* __restrict__ W1,
                                          const float* __restrict__ W2,
                                          uint16_t* __restrict__ Wf1,
                                          uint16_t* __restrict__ Wf2,
                                          float* __restrict__ g_out, int nbZ,
                                          uint32_t* __restrict__ zw) {
    int bid = blockIdx.x, t = threadIdx.x;
    if (bid < nbC) {
        int i = bid * 512 + t;
        if (i <= N) cursor[i] = 0;
        if (bid == 0 && t < 64) zw[(size_t)N * 64 + t] = 0u;  // pad row = 0
    } else if (bid < nbC + 8) {
        int tid = (bid - nbC) * 512 + t;        // 0..4095
        const float* W = (tid & 2048) ? W2 : W1;
        uint16_t* O = (tid & 2048) ? Wf2 : Wf1;
        int q16 = tid & 2047;
        int lane = q16 & 63, n0ks = q16 >> 6;
        int n0 = n0ks >> 2, ks = n0ks & 3;
        int m = lane & 15, quad = lane >> 4;
        int nn = n0 * 16 + m;
        int kkb = ks * 32 + quad * 8;
        uint16_t v[8];
#pragma unroll
        for (int j = 0; j < 8; ++j) v[j] = bf16rne(W[(kkb + j) * 128 + nn]);
        *(short8*)&O[q16 * 8] = *(short8*)v;
    } else {
        int idx = (bid - nbC - 8) * 512 + t;    // nbZ blocks x 512 float4s
        ((float4*)g_out)[idx] = make_float4(0.f, 0.f, 0.f, 0.f);
    }
}

// ---- gemm body (NW waves, M = NW*16 tile) ----
template <int NW>
__device__ __forceinline__ void gemm_body(const float* Xf, const uint16_t* Xb,
                                          const uint16_t* __restrict__ Wf,
                                          uint16_t* __restrict__ Y, int nrows,
                                          uint16_t* Wl, int bid, int t) {
    int lane = t & 63, w = t >> 6;
    int row0 = bid * (NW * 16);
    for (int c = t; c < 2048; c += NW * 64)
        *(short8*)&Wl[c * 8] = *(const short8*)&Wf[c * 8];
    int m = lane & 15, quad = lane >> 4;
    int arow = row0 + w * 16 + m;
    bool rowok = arow < nrows;
    short8 a[4];
    short8 zer = {0, 0, 0, 0, 0, 0, 0, 0};
    if (Xb) {
        const uint16_t* aptr = Xb + (size_t)arow * 128 + quad * 8;
#pragma unroll
        for (int ks = 0; ks < 4; ++ks)
            a[ks] = rowok ? *(const short8*)(aptr + ks * 32) : zer;
    } else {
        const float* ap = Xf + (size_t)arow * 128 + quad * 8;
#pragma unroll
        for (int ks = 0; ks < 4; ++ks) {
            if (rowok) {
                float4 u0 = *(const float4*)(ap + ks * 32);
                float4 u1 = *(const float4*)(ap + ks * 32 + 4);
                uint32_t q[4];
                q[0] = (uint32_t)bf16rne(u0.x) | ((uint32_t)bf16rne(u0.y) << 16);
                q[1] = (uint32_t)bf16rne(u0.z) | ((uint32_t)bf16rne(u0.w) << 16);
                q[2] = (uint32_t)bf16rne(u1.x) | ((uint32_t)bf16rne(u1.y) << 16);
                q[3] = (uint32_t)bf16rne(u1.z) | ((uint32_t)bf16rne(u1.w) << 16);
                a[ks] = *(short8*)q;
            } else a[ks] = zer;
        }
    }
    __syncthreads();

    f32x4 acc[8];
#pragma unroll
    for (int i = 0; i < 8; ++i) acc[i] = (f32x4){0.f, 0.f, 0.f, 0.f};
#pragma unroll
    for (int ks = 0; ks < 4; ++ks)
#pragma unroll
        for (int n0 = 0; n0 < 8; ++n0) {
            short8 b = *(short8*)&Wl[((n0 * 4 + ks) * 64 + lane) * 8];
            acc[n0] = __builtin_amdgcn_mfma_f32_16x16x32_bf16(a[ks], b, acc[n0], 0, 0, 0);
        }
    __syncthreads();  // all waves done reading Wl; reuse as epilogue buffer

    uint16_t* Ep = Wl;  // [NW*16][136] view, wave-private 16-row bands
#pragma unroll
    for (int n0 = 0; n0 < 8; ++n0)
#pragma unroll
        for (int r = 0; r < 4; ++r)
            Ep[(w * 16 + quad * 4 + r) * 136 + n0 * 16 + m] = bf16rne(acc[n0][r]);
    for (int r16 = 0; r16 < 16; ++r16) {
        int row = row0 + w * 16 + r16;
        if (row < nrows) {
            uint32_t v = *(uint32_t*)&Ep[(w * 16 + r16) * 136 + lane * 2];
            ((uint32_t*)Y)[(size_t)row * 64 + lane] = v;
        }
    }
}

// ---- fill body (512 thr): 8 edges/thread; bucket write (u16) + deg count ----
__device__ __forceinline__ void fill_body(const int* __restrict__ src, const int* __restrict__ dst,
                                          int* __restrict__ cursor, uint16_t* __restrict__ col,
                                          int E, int fb, int t) {
    int base = fb * 4096 + t;
    int d[8], s[8], p[8];
#pragma unroll
    for (int k = 0; k < 8; ++k) {
        int e = base + k * 512;
        d[k] = (e < E) ? dst[e] : -1;
        s[k] = (e < E) ? src[e] : 0;
    }
#pragma unroll
    for (int k = 0; k < 8; ++k) if (d[k] >= 0) p[k] = atomicAdd(&cursor[d[k]], 1);
#pragma unroll
    for (int k = 0; k < 8; ++k)
        if (d[k] >= 0 && p[k] < CAP) col[(size_t)d[k] * CAP + p[k]] = (uint16_t)s[k];
}

// ---- K5: gemm1 (+) fill interleaved ----
__global__ __launch_bounds__(512, 8) void k5(const float* __restrict__ X,
                                             const uint16_t* __restrict__ Wf,
                                             uint16_t* __restrict__ Y, int nrows, int gemmGrid,
                                             const int* __restrict__ src, const int* __restrict__ dst,
                                             int* __restrict__ cursor, uint16_t* __restrict__ col,
                                             int E, int fillGrid) {
    __shared__ uint16_t Wl[17408];
    int bid = blockIdx.x, t = threadIdx.x;
    int mn = min(gemmGrid, fillGrid), mn2 = 2 * mn;
    int role, idx;
    if (bid < mn2) { role = bid & 1; idx = bid >> 1; }
    else { role = (gemmGrid > fillGrid) ? 0 : 1; idx = bid - mn2 + mn; }
    if (role == 0) gemm_body<8>(X, nullptr, Wf, Y, nrows, Wl, idx, t);
    else fill_body(src, dst, cursor, col, E, idx, t);
}

// ---- gemm standalone (layer 2): M=64 tile, 256 thr ----
__global__ __launch_bounds__(256, 4) void gemm2k(const uint16_t* __restrict__ Xb,
                                                 const uint16_t* __restrict__ Wf,
                                                 uint16_t* __restrict__ Y, int nrows) {
    __shared__ uint16_t Wl[17408];
    gemm_body<4>(nullptr, Xb, Wf, Y, nrows, Wl, blockIdx.x, threadIdx.x);
}

// ---- agg + fused pool: 4 waves = 4 nodes; bucket in 1 VGPR, readlane ->
//      SGPR-addressed gathers; pad-to-8 with zero row (id=n) -> no tail loop ----
__global__ __launch_bounds__(256) void aggp(const uint32_t* __restrict__ zw,
                                            const int* __restrict__ cnt,
                                            const uint16_t* __restrict__ col,
                                            const float* __restrict__ bias,
                                            const float* __restrict__ alpha,
                                            const int* __restrict__ batch,
                                            float* __restrict__ gout, int col_off,
                                            uint32_t* __restrict__ z1b,
                                            float* __restrict__ zoutf,
                                            int mode, int n) {
    __shared__ int gsh[4];
    __shared__ float red[4][128];
    int wv = threadIdx.x >> 6;
    int lane = threadIdx.x & 63;
    int node = blockIdx.x * 4 + wv;
    bool valid = node < n;
    int nc = __builtin_amdgcn_readfirstlane(valid ? node : (n - 1));
    int c = lane * 2;
    int deg = cnt[nc];
    float di = rsqrtf((float)(deg + 1));
    uint32_t sv = zw[(size_t)nc * 64 + lane];
    float ax = di * bf_lo(sv), ay = di * bf_hi(sv);  // self term (x di again at end)
    float bx = 0.f, by = 0.f;
    int len = min(deg, CAP);
    int len8 = (len + 7) & ~7;   // padded length (pads -> id n, zero row)
    // whole bucket (96 x u16 = 48 x u32) into one VGPR: lane l holds ids 2l,2l+1
    const uint32_t* cbu = (const uint32_t*)(col + (size_t)nc * CAP);
    uint32_t cc = cbu[lane < 48 ? lane : 0];
    int e = 0;
    for (; e + 16 <= len8; e += 16) {
        int h = e >> 1;
        uint32_t q0 = (uint32_t)__builtin_amdgcn_readlane((int)cc, h);
        uint32_t q1 = (uint32_t)__builtin_amdgcn_readlane((int)cc, h + 1);
        uint32_t q2 = (uint32_t)__builtin_amdgcn_readlane((int)cc, h + 2);
        uint32_t q3 = (uint32_t)__builtin_amdgcn_readlane((int)cc, h + 3);
        uint32_t q4 = (uint32_t)__builtin_amdgcn_readlane((int)cc, h + 4);
        uint32_t q5 = (uint32_t)__builtin_amdgcn_readlane((int)cc, h + 5);
        uint32_t q6 = (uint32_t)__builtin_amdgcn_readlane((int)cc, h + 6);
        uint32_t q7 = (uint32_t)__builtin_amdgcn_readlane((int)cc, h + 7);
        int s0  = (e +  0 < len) ? (int)(q0 & 0xffffu) : n;
        int s1  = (e +  1 < len) ? (int)(q0 >> 16)     : n;
        int s2  = (e +  2 < len) ? (int)(q1 & 0xffffu) : n;
        int s3  = (e +  3 < len) ? (int)(q1 >> 16)     : n;
        int s4  = (e +  4 < len) ? (int)(q2 & 0xffffu) : n;
        int s5  = (e +  5 < len) ? (int)(q2 >> 16)     : n;
        int s6  = (e +  6 < len) ? (int)(q3 & 0xffffu) : n;
        int s7  = (e +  7 < len) ? (int)(q3 >> 16)     : n;
        int s8  = (e +  8 < len) ? (int)(q4 & 0xffffu) : n;
        int s9  = (e +  9 < len) ? (int)(q4 >> 16)     : n;
        int s10 = (e + 10 < len) ? (int)(q5 & 0xffffu) : n;
        int s11 = (e + 11 < len) ? (int)(q5 >> 16)     : n;
        int s12 = (e + 12 < len) ? (int)(q6 & 0xffffu) : n;
        int s13 = (e + 13 < len) ? (int)(q6 >> 16)     : n;
        int s14 = (e + 14 < len) ? (int)(q7 & 0xffffu) : n;
        int s15 = (e + 15 < len) ? (int)(q7 >> 16)     : n;
        uint32_t v0  = zw[(size_t)s0  * 64 + lane];
        uint32_t v1  = zw[(size_t)s1  * 64 + lane];
        uint32_t v2  = zw[(size_t)s2  * 64 + lane];
        uint32_t v3  = zw[(size_t)s3  * 64 + lane];
        uint32_t v4  = zw[(size_t)s4  * 64 + lane];
        uint32_t v5  = zw[(size_t)s5  * 64 + lane];
        uint32_t v6  = zw[(size_t)s6  * 64 + lane];
        uint32_t v7  = zw[(size_t)s7  * 64 + lane];
        uint32_t v8  = zw[(size_t)s8  * 64 + lane];
        uint32_t v9  = zw[(size_t)s9  * 64 + lane];
        uint32_t v10 = zw[(size_t)s10 * 64 + lane];
        uint32_t v11 = zw[(size_t)s11 * 64 + lane];
        uint32_t v12 = zw[(size_t)s12 * 64 + lane];
        uint32_t v13 = zw[(size_t)s13 * 64 + lane];
        uint32_t v14 = zw[(size_t)s14 * 64 + lane];
        uint32_t v15 = zw[(size_t)s15 * 64 + lane];
        float w0  = rsqrtf((float)(cnt[s0]  + 1));
        float w1  = rsqrtf((float)(cnt[s1]  + 1));
        float w2  = rsqrtf((float)(cnt[s2]  + 1));
        float w3  = rsqrtf((float)(cnt[s3]  + 1));
        float w4  = rsqrtf((float)(cnt[s4]  + 1));
        float w5  = rsqrtf((float)(cnt[s5]  + 1));
        float w6  = rsqrtf((float)(cnt[s6]  + 1));
        float w7  = rsqrtf((float)(cnt[s7]  + 1));
        float w8  = rsqrtf((float)(cnt[s8]  + 1));
        float w9  = rsqrtf((float)(cnt[s9]  + 1));
        float w10 = rsqrtf((float)(cnt[s10] + 1));
        float w11 = rsqrtf((float)(cnt[s11] + 1));
        float w12 = rsqrtf((float)(cnt[s12] + 1));
        float w13 = rsqrtf((float)(cnt[s13] + 1));
        float w14 = rsqrtf((float)(cnt[s14] + 1));
        float w15 = rsqrtf((float)(cnt[s15] + 1));
        ax += w0  * bf_lo(v0);  ay += w0  * bf_hi(v0);
        bx += w1  * bf_lo(v1);  by += w1  * bf_hi(v1);
        ax += w2  * bf_lo(v2);  ay += w2  * bf_hi(v2);
        bx += w3  * bf_lo(v3);  by += w3  * bf_hi(v3);
        ax += w4  * bf_lo(v4);  ay += w4  * bf_hi(v4);
        bx += w5  * bf_lo(v5);  by += w5  * bf_hi(v5);
        ax += w6  * bf_lo(v6);  ay += w6  * bf_hi(v6);
        bx += w7  * bf_lo(v7);  by += w7  * bf_hi(v7);
        ax += w8  * bf_lo(v8);  ay += w8  * bf_hi(v8);
        bx += w9  * bf_lo(v9);  by += w9  * bf_hi(v9);
        ax += w10 * bf_lo(v10); ay += w10 * bf_hi(v10);
        bx += w11 * bf_lo(v11); by += w11 * bf_hi(v11);
        ax += w12 * bf_lo(v12); ay += w12 * bf_hi(v12);
        bx += w13 * bf_lo(v13); by += w13 * bf_hi(v13);
        ax += w14 * bf_lo(v14); ay += w14 * bf_hi(v14);
        bx += w15 * bf_lo(v15); by += w15 * bf_hi(v15);
    }
    if (e < len8) {  // one remaining 8-batch (padded)
        int h = e >> 1;
        uint32_t q0 = (uint32_t)__builtin_amdgcn_readlane((int)cc, h);
        uint32_t q1 = (uint32_t)__builtin_amdgcn_readlane((int)cc, h + 1);
        uint32_t q2 = (uint32_t)__builtin_amdgcn_readlane((int)cc, h + 2);
        uint32_t q3 = (uint32_t)__builtin_amdgcn_readlane((int)cc, h + 3);
        int s0 = (e + 0 < len) ? (int)(q0 & 0xffffu) : n;
        int s1 = (e + 1 < len) ? (int)(q0 >> 16)     : n;
        int s2 = (e + 2 < len) ? (int)(q1 & 0xffffu) : n;
        int s3 = (e + 3 < len) ? (int)(q1 >> 16)     : n;
        int s4 = (e + 4 < len) ? (int)(q2 & 0xffffu) : n;
        int s5 = (e + 5 < len) ? (int)(q2 >> 16)     : n;
        int s6 = (e + 6 < len) ? (int)(q3 & 0xffffu) : n;
        int s7 = (e + 7 < len) ? (int)(q3 >> 16)     : n;
        uint32_t v0 = zw[(size_t)s0 * 64 + lane];
        uint32_t v1 = zw[(size_t)s1 * 64 + lane];
        uint32_t v2 = zw[(size_t)s2 * 64 + lane];
        uint32_t v3 = zw[(size_t)s3 * 64 + lane];
        uint32_t v4 = zw[(size_t)s4 * 64 + lane];
        uint32_t v5 = zw[(size_t)s5 * 64 + lane];
        uint32_t v6 = zw[(size_t)s6 * 64 + lane];
        uint32_t v7 = zw[(size_t)s7 * 64 + lane];
        float w0 = rsqrtf((float)(cnt[s0] + 1));
        float w1 = rsqrtf((float)(cnt[s1] + 1));
        float w2 = rsqrtf((float)(cnt[s2] + 1));
        float w3 = rsqrtf((float)(cnt[s3] + 1));
        float w4 = rsqrtf((float)(cnt[s4] + 1));
        float w5 = rsqrtf((float)(cnt[s5] + 1));
        float w6 = rsqrtf((float)(cnt[s6] + 1));
        float w7 = rsqrtf((float)(cnt[s7] + 1));
        ax += w0 * bf_lo(v0); ay += w0 * bf_hi(v0);
        bx += w1 * bf_lo(v1); by += w1 * bf_hi(v1);
        ax += w2 * bf_lo(v2); ay += w2 * bf_hi(v2);
        bx += w3 * bf_lo(v3); by += w3 * bf_hi(v3);
        ax += w4 * bf_lo(v4); ay += w4 * bf_hi(v4);
        bx += w5 * bf_lo(v5); by += w5 * bf_hi(v5);
        ax += w6 * bf_lo(v6); ay += w6 * bf_hi(v6);
        bx += w7 * bf_lo(v7); by += w7 * bf_hi(v7);
    }
    ax += bx; ay += by;
    float zx = di * ax + bias[c];
    float zy = di * ay + bias[c + 1];
    float px = alpha[c], py = alpha[c + 1];
    zx = zx > 0.f ? zx : px * zx;
    zy = zy > 0.f ? zy : py * zy;

    if (valid) {
        if (mode == 0) {
            uint32_t pk = (uint32_t)bf16rne(zx) | ((uint32_t)bf16rne(zy) << 16);
            z1b[(size_t)nc * 64 + lane] = pk;
        } else {
            ((float2*)zoutf)[(size_t)nc * 64 + lane] = make_float2(zx, zy);
        }
    }

    int g = batch[nc];
    float cx = valid ? zx : 0.f, cy = valid ? zy : 0.f;
    if (lane == 0) gsh[wv] = valid ? g : -1 - wv;
    __syncthreads();
    bool uni = (gsh[0] == gsh[1]) && (gsh[1] == gsh[2]) && (gsh[2] == gsh[3]);
    if (uni) {
        red[wv][c] = cx; red[wv][c + 1] = cy;
        __syncthreads();
        if (wv == 0) {
            float sx = red[0][c] + red[1][c] + red[2][c] + red[3][c];
            float sy = red[0][c + 1] + red[1][c + 1] + red[2][c + 1] + red[3][c + 1];
            float* base = &gout[(size_t)g * 256 + col_off];
            atomicAdd(&base[c], sx);
            atomicAdd(&base[c + 1], sy);
        }
    } else {
        __syncthreads();
        if (valid) {
            float* base = &gout[(size_t)g * 256 + col_off];
            atomicAdd(&base[c], cx);
            atomicAdd(&base[c + 1], cy);
        }
    }
}

extern "C" void kernel_launch(void* const* d_in, const int* in_sizes, int n_in,
                              void* d_out, int out_size, void* d_ws, size_t ws_size,
                              hipStream_t stream) {
    const float* x     = (const float*)d_in[0];
    const int*   eidx  = (const int*)d_in[1];
    const int*   batch = (const int*)d_in[2];
    const float* W1    = (const float*)d_in[3];
    const float* b1    = (const float*)d_in[4];
    const float* W2    = (const float*)d_in[5];
    const float* b2    = (const float*)d_in[6];
    const float* alpha = (const float*)d_in[7];

    const int N = in_sizes[2];
    const int E = in_sizes[1] / 2;
    const int G = (out_size - N * 128) / 256;

    const int* src = eidx;
    const int* dst = eidx + E;

    char* ws = (char*)d_ws;
    size_t off = 0;
    auto alloc = [&](size_t bytes) { void* q = ws + off; off = (off + bytes + 255) & ~(size_t)255; return q; };
    int*      cursor = (int*)alloc((size_t)(N + 1) * 4);
    uint16_t* col    = (uint16_t*)alloc((size_t)N * CAP * 2);
    uint32_t* zw     = (uint32_t*)alloc((size_t)(N + 1) * 128 * 2);  // +1 pad row (zeroed)
    uint32_t* z1b    = (uint32_t*)alloc((size_t)N * 128 * 2);
    uint16_t* Wf1    = (uint16_t*)alloc(128 * 128 * 2);
    uint16_t* Wf2    = (uint16_t*)alloc(128 * 128 * 2);

    float* z_out = (float*)d_out;
    float* g_out = (float*)d_out + (size_t)N * 128;

    int nbC      = (N + 512) / 512;            // cursor zero (N+1 entries)
    int nbZ      = (G * 256 / 4 + 511) / 512;  // g_out zero (float4)
    int fillGrid = (E + 4095) / 4096;          // 8 edges/thread x 512
    int gemmGrid = (N + 127) / 128;            // M=128 tiles x 512 thr (k5)
    int gemm2Grid = (N + 63) / 64;             // M=64 tiles x 256 thr
    int aggGrid  = (N + 3) / 4;

    k0<<<nbC + 8 + nbZ, 512, 0, stream>>>(cursor, nbC, N, W1, W2, Wf1, Wf2, g_out, nbZ, zw);
    k5<<<gemmGrid + fillGrid, 512, 0, stream>>>(x, Wf1, (uint16_t*)zw, N, gemmGrid,
                                                src, dst, cursor, col, E, fillGrid);
    aggp<<<aggGrid, 256, 0, stream>>>(zw, cursor, col, b1, alpha, batch,
                                      g_out, 0, z1b, nullptr, 0, N);
    gemm2k<<<gemm2Grid, 256, 0, stream>>>((const uint16_t*)z1b, Wf2, (uint16_t*)zw, N);
    aggp<<<aggGrid, 256, 0, stream>>>(zw, cursor, col, b2, alpha, batch,
                                      g_out, 128, nullptr, z_out, 1, N);
}

// Round 3
// 228.256 us; speedup vs baseline: 1.0728x; 1.0728x over previous
//
#include <hip/hip_runtime.h>
#include <stdint.h>

// ---------------------------------------------------------------------------
// GCN 2-layer. R13: revert R12 regressions (fill back to 4 edges/thread so
// fillGrid==gemmGrid interleave is balanced; gemm2k back to M=128/512thr).
// Keep aggp pad-to-8 + 16-deep MLP. NEW: fold dinv[s] into zw2 rows at the
// gemm2k epilogue (deg final by then) -> aggp2<PS=true> drops cnt gathers,
// cvt and rsqrt per edge (FMA->ADD). aggp1 unchanged (fill concurrent with
// gemm1 forbids the fold for layer 1).
// 5 dispatches: k0(zero cursor+zwpad+g_out | prep_w) -> k5(gemm1 (+) fill) ->
// aggp<false> -> gemm2k(dinv-fold) -> aggp<true>.
// ---------------------------------------------------------------------------

#define CAP 96

typedef __attribute__((ext_vector_type(8))) short short8;
typedef __attribute__((ext_vector_type(4))) float f32x4;

__device__ __forceinline__ uint16_t bf16rne(float f) {
    uint32_t u = __float_as_uint(f);
    uint32_t r = (u + 0x7fffu + ((u >> 16) & 1u)) >> 16;
    return (uint16_t)r;
}
__device__ __forceinline__ float bf_lo(uint32_t v) { return __uint_as_float(v << 16); }
__device__ __forceinline__ float bf_hi(uint32_t v) { return __uint_as_float(v & 0xffff0000u); }

// ---- K0 (512 thr): zero cursor(N+1) + zw pad row | prep_w | zero g_out ----
__global__ __launch_bounds__(512) void k0(int* __restrict__ cursor, int nbC, int N,
                                          const float* __restrict__ W1,
                                          const float* __restrict__ W2,
                                          uint16_t* __restrict__ Wf1,
                                          uint16_t* __restrict__ Wf2,
                                          float* __restrict__ g_out, int nbZ,
                                          uint32_t* __restrict__ zw) {
    int bid = blockIdx.x, t = threadIdx.x;
    if (bid < nbC) {
        int i = bid * 512 + t;
        if (i <= N) cursor[i] = 0;
        if (bid == 0 && t < 64) zw[(size_t)N * 64 + t] = 0u;  // pad row = 0
    } else if (bid < nbC + 8) {
        int tid = (bid - nbC) * 512 + t;        // 0..4095
        const float* W = (tid & 2048) ? W2 : W1;
        uint16_t* O = (tid & 2048) ? Wf2 : Wf1;
        int q16 = tid & 2047;
        int lane = q16 & 63, n0ks = q16 >> 6;
        int n0 = n0ks >> 2, ks = n0ks & 3;
        int m = lane & 15, quad = lane >> 4;
        int nn = n0 * 16 + m;
        int kkb = ks * 32 + quad * 8;
        uint16_t v[8];
#pragma unroll
        for (int j = 0; j < 8; ++j) v[j] = bf16rne(W[(kkb + j) * 128 + nn]);
        *(short8*)&O[q16 * 8] = *(short8*)v;
    } else {
        int idx = (bid - nbC - 8) * 512 + t;    // nbZ blocks x 512 float4s
        ((float4*)g_out)[idx] = make_float4(0.f, 0.f, 0.f, 0.f);
    }
}

// ---- gemm body (8 waves, M=128 tile); optional dinv-fold epilogue ----
__device__ __forceinline__ void gemm_body(const float* Xf, const uint16_t* Xb,
                                          const uint16_t* __restrict__ Wf,
                                          uint16_t* __restrict__ Y, int nrows,
                                          const int* __restrict__ cnt,  // nullptr -> no fold
                                          uint16_t* Wl, int bid, int t) {
    int lane = t & 63, w = t >> 6;
    int row0 = bid * 128;
    for (int c = t; c < 2048; c += 512)
        *(short8*)&Wl[c * 8] = *(const short8*)&Wf[c * 8];
    int m = lane & 15, quad = lane >> 4;
    int arow = row0 + w * 16 + m;
    bool rowok = arow < nrows;
    short8 a[4];
    short8 zer = {0, 0, 0, 0, 0, 0, 0, 0};
    if (Xb) {
        const uint16_t* aptr = Xb + (size_t)arow * 128 + quad * 8;
#pragma unroll
        for (int ks = 0; ks < 4; ++ks)
            a[ks] = rowok ? *(const short8*)(aptr + ks * 32) : zer;
    } else {
        const float* ap = Xf + (size_t)arow * 128 + quad * 8;
#pragma unroll
        for (int ks = 0; ks < 4; ++ks) {
            if (rowok) {
                float4 u0 = *(const float4*)(ap + ks * 32);
                float4 u1 = *(const float4*)(ap + ks * 32 + 4);
                uint32_t q[4];
                q[0] = (uint32_t)bf16rne(u0.x) | ((uint32_t)bf16rne(u0.y) << 16);
                q[1] = (uint32_t)bf16rne(u0.z) | ((uint32_t)bf16rne(u0.w) << 16);
                q[2] = (uint32_t)bf16rne(u1.x) | ((uint32_t)bf16rne(u1.y) << 16);
                q[3] = (uint32_t)bf16rne(u1.z) | ((uint32_t)bf16rne(u1.w) << 16);
                a[ks] = *(short8*)q;
            } else a[ks] = zer;
        }
    }
    __syncthreads();

    f32x4 acc[8];
#pragma unroll
    for (int i = 0; i < 8; ++i) acc[i] = (f32x4){0.f, 0.f, 0.f, 0.f};
#pragma unroll
    for (int ks = 0; ks < 4; ++ks)
#pragma unroll
        for (int n0 = 0; n0 < 8; ++n0) {
            short8 b = *(short8*)&Wl[((n0 * 4 + ks) * 64 + lane) * 8];
            acc[n0] = __builtin_amdgcn_mfma_f32_16x16x32_bf16(a[ks], b, acc[n0], 0, 0, 0);
        }
    __syncthreads();  // all 8 waves done reading Wl; reuse as epilogue buffer

    // per-lane output rows are (quad*4 + r); fold dinv there if requested
    float dsc[4] = {1.f, 1.f, 1.f, 1.f};
    if (cnt) {
#pragma unroll
        for (int r = 0; r < 4; ++r) {
            int gr = row0 + w * 16 + quad * 4 + r;
            int d = (gr < nrows) ? cnt[gr] : 0;
            dsc[r] = rsqrtf((float)(d + 1));
        }
    }

    uint16_t* Ep = Wl;  // [128][136] view, wave-private 16-row bands
#pragma unroll
    for (int n0 = 0; n0 < 8; ++n0)
#pragma unroll
        for (int r = 0; r < 4; ++r)
            Ep[(w * 16 + quad * 4 + r) * 136 + n0 * 16 + m] = bf16rne(acc[n0][r] * dsc[r]);
    for (int r16 = 0; r16 < 16; ++r16) {
        int row = row0 + w * 16 + r16;
        if (row < nrows) {
            uint32_t v = *(uint32_t*)&Ep[(w * 16 + r16) * 136 + lane * 2];
            ((uint32_t*)Y)[(size_t)row * 64 + lane] = v;
        }
    }
}

// ---- fill body (512 thr): 4 edges/thread; bucket write (u16) + deg count ----
__device__ __forceinline__ void fill_body(const int* __restrict__ src, const int* __restrict__ dst,
                                          int* __restrict__ cursor, uint16_t* __restrict__ col,
                                          int E, int fb, int t) {
    int base = fb * 2048 + t;
    int d[4], s[4], p[4];
#pragma unroll
    for (int k = 0; k < 4; ++k) {
        int e = base + k * 512;
        d[k] = (e < E) ? dst[e] : -1;
        s[k] = (e < E) ? src[e] : 0;
    }
#pragma unroll
    for (int k = 0; k < 4; ++k) if (d[k] >= 0) p[k] = atomicAdd(&cursor[d[k]], 1);
#pragma unroll
    for (int k = 0; k < 4; ++k)
        if (d[k] >= 0 && p[k] < CAP) col[(size_t)d[k] * CAP + p[k]] = (uint16_t)s[k];
}

// ---- K5: gemm1 (+) fill interleaved ----
__global__ __launch_bounds__(512, 8) void k5(const float* __restrict__ X,
                                             const uint16_t* __restrict__ Wf,
                                             uint16_t* __restrict__ Y, int nrows, int gemmGrid,
                                             const int* __restrict__ src, const int* __restrict__ dst,
                                             int* __restrict__ cursor, uint16_t* __restrict__ col,
                                             int E, int fillGrid) {
    __shared__ uint16_t Wl[17408];
    int bid = blockIdx.x, t = threadIdx.x;
    int mn = min(gemmGrid, fillGrid), mn2 = 2 * mn;
    int role, idx;
    if (bid < mn2) { role = bid & 1; idx = bid >> 1; }
    else { role = (gemmGrid > fillGrid) ? 0 : 1; idx = bid - mn2 + mn; }
    if (role == 0) gemm_body(X, nullptr, Wf, Y, nrows, nullptr, Wl, idx, t);
    else fill_body(src, dst, cursor, col, E, idx, t);
}

// ---- gemm standalone (layer 2): M=128, 512 thr, dinv folded into output ----
__global__ __launch_bounds__(512, 8) void gemm2k(const uint16_t* __restrict__ Xb,
                                                 const uint16_t* __restrict__ Wf,
                                                 uint16_t* __restrict__ Y, int nrows,
                                                 const int* __restrict__ cnt) {
    __shared__ uint16_t Wl[17408];
    gemm_body(nullptr, Xb, Wf, Y, nrows, cnt, Wl, blockIdx.x, threadIdx.x);
}

// ---- agg + fused pool: 4 waves = 4 nodes; bucket in 1 VGPR, readlane ->
//      SGPR-addressed gathers; pad-to-8 via zero row (id=n). PS=true: zw rows
//      pre-scaled by dinv[s] (layer 2) -> no cnt gather / rsqrt / cvt ----
template <bool PS>
__global__ __launch_bounds__(256) void aggp(const uint32_t* __restrict__ zw,
                                            const int* __restrict__ cnt,
                                            const uint16_t* __restrict__ col,
                                            const float* __restrict__ bias,
                                            const float* __restrict__ alpha,
                                            const int* __restrict__ batch,
                                            float* __restrict__ gout, int col_off,
                                            uint32_t* __restrict__ z1b,
                                            float* __restrict__ zoutf,
                                            int mode, int n) {
    __shared__ int gsh[4];
    __shared__ float red[4][128];
    int wv = threadIdx.x >> 6;
    int lane = threadIdx.x & 63;
    int node = blockIdx.x * 4 + wv;
    bool valid = node < n;
    int nc = __builtin_amdgcn_readfirstlane(valid ? node : (n - 1));
    int c = lane * 2;
    int deg = cnt[nc];
    float di = rsqrtf((float)(deg + 1));
    uint32_t sv = zw[(size_t)nc * 64 + lane];
    // self term: PS rows already carry dinv[nc]; non-PS needs explicit di
    float sw = PS ? 1.f : di;
    float ax = sw * bf_lo(sv), ay = sw * bf_hi(sv);
    float bx = 0.f, by = 0.f;
    int len = min(deg, CAP);
    int len8 = (len + 7) & ~7;   // padded length (pads -> id n, zero row)
    // whole bucket (96 x u16 = 48 x u32) into one VGPR: lane l holds ids 2l,2l+1
    const uint32_t* cbu = (const uint32_t*)(col + (size_t)nc * CAP);
    uint32_t cc = cbu[lane < 48 ? lane : 0];
    int e = 0;
    for (; e + 16 <= len8; e += 16) {
        int h = e >> 1;
        int s[16];
#pragma unroll
        for (int j = 0; j < 8; ++j) {
            uint32_t q = (uint32_t)__builtin_amdgcn_readlane((int)cc, h + j);
            s[2 * j]     = (e + 2 * j     < len) ? (int)(q & 0xffffu) : n;
            s[2 * j + 1] = (e + 2 * j + 1 < len) ? (int)(q >> 16)     : n;
        }
        uint32_t v[16];
#pragma unroll
        for (int j = 0; j < 16; ++j) v[j] = zw[(size_t)s[j] * 64 + lane];
        float wg[16];
#pragma unroll
        for (int j = 0; j < 16; ++j) wg[j] = PS ? 1.f : rsqrtf((float)(cnt[s[j]] + 1));
#pragma unroll
        for (int j = 0; j < 16; ++j) {
            if (j & 1) { bx += wg[j] * bf_lo(v[j]); by += wg[j] * bf_hi(v[j]); }
            else       { ax += wg[j] * bf_lo(v[j]); ay += wg[j] * bf_hi(v[j]); }
        }
    }
    if (e < len8) {  // one remaining 8-batch (padded)
        int h = e >> 1;
        int s[8];
#pragma unroll
        for (int j = 0; j < 4; ++j) {
            uint32_t q = (uint32_t)__builtin_amdgcn_readlane((int)cc, h + j);
            s[2 * j]     = (e + 2 * j     < len) ? (int)(q & 0xffffu) : n;
            s[2 * j + 1] = (e + 2 * j + 1 < len) ? (int)(q >> 16)     : n;
        }
        uint32_t v[8];
#pragma unroll
        for (int j = 0; j < 8; ++j) v[j] = zw[(size_t)s[j] * 64 + lane];
        float wg[8];
#pragma unroll
        for (int j = 0; j < 8; ++j) wg[j] = PS ? 1.f : rsqrtf((float)(cnt[s[j]] + 1));
#pragma unroll
        for (int j = 0; j < 8; ++j) {
            if (j & 1) { bx += wg[j] * bf_lo(v[j]); by += wg[j] * bf_hi(v[j]); }
            else       { ax += wg[j] * bf_lo(v[j]); ay += wg[j] * bf_hi(v[j]); }
        }
    }
    ax += bx; ay += by;
    float zx = di * ax + bias[c];
    float zy = di * ay + bias[c + 1];
    float px = alpha[c], py = alpha[c + 1];
    zx = zx > 0.f ? zx : px * zx;
    zy = zy > 0.f ? zy : py * zy;

    if (valid) {
        if (mode == 0) {
            uint32_t pk = (uint32_t)bf16rne(zx) | ((uint32_t)bf16rne(zy) << 16);
            z1b[(size_t)nc * 64 + lane] = pk;
        } else {
            ((float2*)zoutf)[(size_t)nc * 64 + lane] = make_float2(zx, zy);
        }
    }

    int g = batch[nc];
    float cx = valid ? zx : 0.f, cy = valid ? zy : 0.f;
    if (lane == 0) gsh[wv] = valid ? g : -1 - wv;
    __syncthreads();
    bool uni = (gsh[0] == gsh[1]) && (gsh[1] == gsh[2]) && (gsh[2] == gsh[3]);
    if (uni) {
        red[wv][c] = cx; red[wv][c + 1] = cy;
        __syncthreads();
        if (wv == 0) {
            float sx = red[0][c] + red[1][c] + red[2][c] + red[3][c];
            float sy = red[0][c + 1] + red[1][c + 1] + red[2][c + 1] + red[3][c + 1];
            float* base = &gout[(size_t)g * 256 + col_off];
            atomicAdd(&base[c], sx);
            atomicAdd(&base[c + 1], sy);
        }
    } else {
        __syncthreads();
        if (valid) {
            float* base = &gout[(size_t)g * 256 + col_off];
            atomicAdd(&base[c], cx);
            atomicAdd(&base[c + 1], cy);
        }
    }
}

extern "C" void kernel_launch(void* const* d_in, const int* in_sizes, int n_in,
                              void* d_out, int out_size, void* d_ws, size_t ws_size,
                              hipStream_t stream) {
    const float* x     = (const float*)d_in[0];
    const int*   eidx  = (const int*)d_in[1];
    const int*   batch = (const int*)d_in[2];
    const float* W1    = (const float*)d_in[3];
    const float* b1    = (const float*)d_in[4];
    const float* W2    = (const float*)d_in[5];
    const float* b2    = (const float*)d_in[6];
    const float* alpha = (const float*)d_in[7];

    const int N = in_sizes[2];
    const int E = in_sizes[1] / 2;
    const int G = (out_size - N * 128) / 256;

    const int* src = eidx;
    const int* dst = eidx + E;

    char* ws = (char*)d_ws;
    size_t off = 0;
    auto alloc = [&](size_t bytes) { void* q = ws + off; off = (off + bytes + 255) & ~(size_t)255; return q; };
    int*      cursor = (int*)alloc((size_t)(N + 1) * 4);
    uint16_t* col    = (uint16_t*)alloc((size_t)N * CAP * 2);
    uint32_t* zw     = (uint32_t*)alloc((size_t)(N + 1) * 128 * 2);  // +1 pad row (zeroed)
    uint32_t* z1b    = (uint32_t*)alloc((size_t)N * 128 * 2);
    uint16_t* Wf1    = (uint16_t*)alloc(128 * 128 * 2);
    uint16_t* Wf2    = (uint16_t*)alloc(128 * 128 * 2);

    float* z_out = (float*)d_out;
    float* g_out = (float*)d_out + (size_t)N * 128;

    int nbC      = (N + 512) / 512;            // cursor zero (N+1 entries)
    int nbZ      = (G * 256 / 4 + 511) / 512;  // g_out zero (float4)
    int fillGrid = (E + 2047) / 2048;          // 4 edges/thread x 512
    int gemmGrid = (N + 127) / 128;            // M=128 tiles x 512 thr
    int aggGrid  = (N + 3) / 4;

    k0<<<nbC + 8 + nbZ, 512, 0, stream>>>(cursor, nbC, N, W1, W2, Wf1, Wf2, g_out, nbZ, zw);
    k5<<<gemmGrid + fillGrid, 512, 0, stream>>>(x, Wf1, (uint16_t*)zw, N, gemmGrid,
                                                src, dst, cursor, col, E, fillGrid);
    aggp<false><<<aggGrid, 256, 0, stream>>>(zw, cursor, col, b1, alpha, batch,
                                             g_out, 0, z1b, nullptr, 0, N);
    gemm2k<<<gemmGrid, 512, 0, stream>>>((const uint16_t*)z1b, Wf2, (uint16_t*)zw, N, cursor);
    aggp<true><<<aggGrid, 256, 0, stream>>>(zw, cursor, col, b2, alpha, batch,
                                            g_out, 128, nullptr, z_out, 1, N);
}